// Round 8
// baseline (22.285 us; speedup 1.0000x reference)
//
#include <hip/hip_runtime.h>
#include <math.h>

#define HNUM 64
#define WNUM 64
#define TNUM 2048
#define B_   64
#define P_   512
#define VD_  128
#define NTAP 128      // truncated ir support: k in [240, 368)  (validated r5)
#define WIN  640      // per-block window: td[T0-112 .. T0+528)

#define LOG2E 1.44269504088896340736f

// ---------------------------------------------------------------------------
// Single fused kernel, 256 blocks x 256 threads, block = (row b, quarter q).
//  q=3 (outputs >= 1536): bins provably < 1024 and conv support t-112 <= 1023
//      -> tdata=0, out=dc; store and exit (no barriers).
//  q<3: Phase A: zero s_w; WAVE-0-ONLY register IR scan (pair affine over
//       taps k=240..367 of ir[k]=e^-lam*ir[k-1]+lam*gauss[k-1-256], 6
//       __shfl_up steps, no barriers — validated r4/r5/r7 math).
//       Phase B: 2 points/thread: cheap dist/bin for all; trilinear + value
//       + 8-bin LDS-atomic scatter only if footprint intersects the window.
//       Phase C: waves 2-3 write tdata; waves 0-1 run the 128-tap conv
//       (rotating float4 window, 4 outputs/lane).
// Exactly 2 __syncthreads per q<3 block.
// ---------------------------------------------------------------------------
__global__ __launch_bounds__(256) void ptr_fused_kernel(
    const float* __restrict__ surf_pos,
    const float* __restrict__ surf_norm,
    const int*   __restrict__ xys,
    const float* __restrict__ phasor,
    const float* __restrict__ albedo_p,
    const float* __restrict__ scale_p,
    const float* __restrict__ sigma_p,
    const float* __restrict__ lamda_p,
    const float* __restrict__ dc_p,
    float* __restrict__ out,     // [B_][TNUM] tdata_out
    float* __restrict__ tdata)   // [B_][TNUM] tdata (2nd output)
{
    __shared__ float s_w[WIN];
    __shared__ float s_ir[NTAP];

    const int tid = threadIdx.x;
    const int blk = blockIdx.x;
    const int b   = blk >> 2;
    const int q   = blk & 3;
    const int T0  = q << 9;
    const float dc = dc_p[0];

    if (q == 3) {
        *reinterpret_cast<float2*>(&tdata[b * TNUM + T0 + tid * 2]) =
            make_float2(0.0f, 0.0f);
        *reinterpret_cast<float2*>(&out[b * TNUM + T0 + tid * 2]) =
            make_float2(dc, dc);
        return;
    }

    // ---- issue both points' position loads early (latency hides Phase A) --
    const int p0 = b * P_ + tid;
    const int p1 = p0 + 256;
    const float px0 = surf_pos[p0 * 3 + 0];
    const float py0 = surf_pos[p0 * 3 + 1];
    const float pz0 = surf_pos[p0 * 3 + 2];
    const float px1 = surf_pos[p1 * 3 + 0];
    const float py1 = surf_pos[p1 * 3 + 1];
    const float pz1 = surf_pos[p1 * 3 + 2];
    const int y = xys[b * 2 + 0];
    const int x = xys[b * 2 + 1];

    // ---- Phase A: zero window + wave-0 register IR scan ----
    if (tid < WIN / 4)
        *reinterpret_cast<float4*>(&s_w[tid * 4]) =
            make_float4(0.0f, 0.0f, 0.0f, 0.0f);

    if (tid < 64) {
        const float sinv = 1.0f / sigma_p[0];
        const float lam  = lamda_p[0];
        const float eneg = __builtin_amdgcn_exp2f(-lam * LOG2E);
        const int k0 = 2 * tid, k1 = 2 * tid + 1;
        const float a0f = (float)(k0 - 17);   // gauss[(k-1)-256] at k=240+k0
        const float a1f = (float)(k1 - 17);
        const float cg  = sinv * 0.3989422804014327f;
        const float g0 = cg * __builtin_amdgcn_exp2f(-0.5f * LOG2E * a0f * a0f * sinv * sinv);
        const float g1 = cg * __builtin_amdgcn_exp2f(-0.5f * LOG2E * a1f * a1f * sinv * sinv);
        const float A0 = (k0 == 0) ? 0.0f : eneg;
        const float B0 = lam * g0;
        const float A1 = eneg;
        const float B1 = lam * g1;
        // pair-combined affine, inclusive shuffle scan over 64 lanes
        float A = A1 * A0;
        float Bv = fmaf(A1, B0, B1);
        #pragma unroll
        for (int d = 1; d < 64; d <<= 1) {
            const float al = __shfl_up(A, d);
            const float bl = __shfl_up(Bv, d);
            if (tid >= d) { Bv = fmaf(A, bl, Bv); A *= al; }
        }
        const float vprev = (tid == 0) ? 0.0f : __shfl_up(Bv, 1);
        const float ir0 = fmaf(A0, vprev, B0);
        const float ir1 = fmaf(A1, ir0, B1);
        s_ir[k0] = ir0;
        s_ir[k1] = ir1;
    }
    __syncthreads();   // barrier 1: s_w zeroed, s_ir ready

    // ---- Phase B: dist for both points; conditional heavy eval + scatter --
    {
        const float wxp = -1.0f + 2.0f * (float)x / 63.0f;
        const float wyp = -1.0f + 2.0f * (float)y / 63.0f;
        const float d1  = sqrtf(wxp * wxp + wyp * wyp + 1.0f);
        const float dxc = wxp - 0.05f;
        const float d4  = sqrtf(dxc * dxc + wyp * wyp + 1.0f);
        const float dwall = d1 + d4;
        const float scale = scale_p[0];
        const int winlo = T0 - 112;
        const int winhi = T0 + 528;

        #pragma unroll
        for (int r = 0; r < 2; ++r) {
            const float px = r ? px1 : px0;
            const float py = r ? py1 : py0;
            const float pz = r ? pz1 : pz0;
            const int   pp = r ? p1  : p0;

            // camera_pos == laser_pos == wall  =>  sv == lv
            const float lvx = wxp - px, lvy = wyp - py, lvz = -pz;
            const float ld2 = lvx * lvx + lvy * lvy + lvz * lvz;
            const float ld  = sqrtf(ld2);
            const float dist = dwall + 2.0f * ld;
            const float tc   = dist * 100.0f;
            const int it0    = (int)floorf(tc) - 3;

            if (it0 + 7 >= winlo && it0 < winhi) {
                const float nx = surf_norm[pp * 3 + 0];
                const float ny = surf_norm[pp * 3 + 1];
                const float nz = surf_norm[pp * 3 + 2];

                // branchless trilinear of clip((albedo+phasor)*mask, 0, 1)
                // (clamped corners carry exactly-zero weight; validated r5)
                const float fx = (px + 1.0f) * 31.5f;
                const float fy = (1.0f - py) * 31.5f;
                const float fz = pz * 63.5f;
                const float x0f = floorf(fx), y0f = floorf(fy), z0f = floorf(fz);
                const float wwx = fx - x0f, wwy = fy - y0f, wwz = fz - z0f;
                const int ix0 = (int)x0f, iy0 = (int)y0f, iz0 = (int)z0f;
                const int ix1 = min(ix0 + 1, WNUM - 1);
                const int iy1 = min(iy0 + 1, HNUM - 1);
                const int iz1 = iz0 + 1;   // fz <= 114.3 -> always < 128

                float interp = 0.0f;
                #pragma unroll
                for (int c = 0; c < 8; ++c) {
                    const int dx = c & 1, dy = (c >> 1) & 1, dz = c >> 2;
                    const int ix = dx ? ix1 : ix0;
                    const int iy = dy ? iy1 : iy0;
                    const int iz = dz ? iz1 : iz0;
                    const int idx = (iy * WNUM + ix) * VD_ + iz;
                    const float ph = phasor[idx];
                    const float al = albedo_p[idx];
                    const float v  = (ph > 0.0f) ? fminf(fmaxf(al + ph, 0.0f), 1.0f)
                                                 : 0.0f;
                    const float w3 = (dx ? wwx : 1.0f - wwx) *
                                     (dy ? wwy : 1.0f - wwy) *
                                     (dz ? wwz : 1.0f - wwz);
                    interp = fmaf(v, w3, interp);
                }

                const float ild = 1.0f / fmaxf(ld, 1e-12f);
                const float lnz = lvz * ild;
                const float dotn = (lvx * nx + lvy * ny + lvz * nz) * ild;
                const float value = scale * interp / (ld2 * ld2) *
                                    (lnz * lnz) * (dotn * dotn);

                // weight = 2^(-4*dbins^2); neglected tail (|db|>=4) <= 2^-64
                #pragma unroll
                for (int k = 0; k < 8; ++k) {
                    const int t = it0 + k;
                    if (t >= winlo && t < winhi) {
                        const float db = (float)t - tc;
                        const float w = __builtin_amdgcn_exp2f(-4.0f * db * db);
                        atomicAdd(&s_w[t - winlo], value * w);
                    }
                }
            }
        }
    }
    __syncthreads();   // barrier 2: window complete

    // ---- Phase C: waves 2-3 write tdata; waves 0-1 convolve ----
    if (tid >= 128) {
        const int i = (tid - 128) * 4;
        *reinterpret_cast<float4*>(&tdata[b * TNUM + T0 + i]) =
            *reinterpret_cast<const float4*>(&s_w[112 + i]);
        return;
    }

    const int l0 = tid * 4;
    float acc0 = 0.0f, acc1 = 0.0f, acc2 = 0.0f, acc3 = 0.0f;
    if (q != 2 || tid < 32) {
        // out[T0+l0+o] tap m uses s_w[l0 + o + 127 - m]
        float4 hi4 = *reinterpret_cast<const float4*>(&s_w[l0 + 128]);
        #pragma unroll
        for (int c = 0; c < 32; ++c) {
            const float4 lo4 = *reinterpret_cast<const float4*>(&s_w[l0 + 124 - 4 * c]);
            const float4 irv = *reinterpret_cast<const float4*>(&s_ir[4 * c]);  // bcast
            acc0 = fmaf(irv.x, lo4.w, acc0); acc1 = fmaf(irv.x, hi4.x, acc1);
            acc2 = fmaf(irv.x, hi4.y, acc2); acc3 = fmaf(irv.x, hi4.z, acc3);
            acc0 = fmaf(irv.y, lo4.z, acc0); acc1 = fmaf(irv.y, lo4.w, acc1);
            acc2 = fmaf(irv.y, hi4.x, acc2); acc3 = fmaf(irv.y, hi4.y, acc3);
            acc0 = fmaf(irv.z, lo4.y, acc0); acc1 = fmaf(irv.z, lo4.z, acc1);
            acc2 = fmaf(irv.z, lo4.w, acc2); acc3 = fmaf(irv.z, hi4.x, acc3);
            acc0 = fmaf(irv.w, lo4.x, acc0); acc1 = fmaf(irv.w, lo4.y, acc1);
            acc2 = fmaf(irv.w, lo4.z, acc2); acc3 = fmaf(irv.w, lo4.w, acc3);
            hi4 = lo4;
        }
    }
    float4 o;
    o.x = acc0 + dc; o.y = acc1 + dc; o.z = acc2 + dc; o.w = acc3 + dc;
    *reinterpret_cast<float4*>(&out[b * TNUM + T0 + l0]) = o;
}

extern "C" void kernel_launch(void* const* d_in, const int* in_sizes, int n_in,
                              void* d_out, int out_size, void* d_ws, size_t ws_size,
                              hipStream_t stream) {
    const float* surf_pos  = (const float*)d_in[0];
    const float* surf_norm = (const float*)d_in[1];
    const int*   xys       = (const int*)  d_in[2];
    const float* phasor    = (const float*)d_in[3];
    const float* albedo    = (const float*)d_in[4];
    const float* scale_p   = (const float*)d_in[5];
    const float* sigma_p   = (const float*)d_in[6];
    const float* lamda_p   = (const float*)d_in[7];
    const float* dc_p      = (const float*)d_in[8];

    float* out   = (float*)d_out;            // [B_][TNUM] tdata_out
    float* tdata = out + B_ * TNUM;          // [B_][TNUM] tdata (2nd output)

    ptr_fused_kernel<<<B_ * 4, 256, 0, stream>>>(
        surf_pos, surf_norm, xys, phasor, albedo, scale_p, sigma_p, lamda_p,
        dc_p, out, tdata);
}